// Round 12
// baseline (175.944 us; speedup 1.0000x reference)
//
#include <hip/hip_runtime.h>

// STKBranch double-softmax attention, R12: f16-workspace + global_load_lds staging.
//   pass0a: K f32 -> f16 (same [h][key][d] layout) into d_ws
//   pass0b: V f32 -> f16 TRANSPOSED [h][d][key] into d_ws
//   main:   K/V tiles staged via 1 global_load_lds(16B) per wave per tile,
//           source-XOR-swizzled so LDS b128 fragment reads are bank-disjoint.
//           2-pass no-max softmax chain (|L|<=~7), Ps wave-private, 1 barrier/tile.
// Math: L = scale*q@k^T ; w = softmax(2L) ; attn = softmax(L*w) ; out = attn@v
// B=4 H=8 N=2048 D=64 fp32 io.

typedef _Float16 f16;
typedef f16 f16x8 __attribute__((ext_vector_type(8)));
typedef float f32x4 __attribute__((ext_vector_type(4)));

#define MFMA(a, b, c) __builtin_amdgcn_mfma_f32_16x16x32_f16((a), (b), (c), 0, 0, 0)
#define EXP2(x) __builtin_amdgcn_exp2f(x)   // v_exp_f32: D = 2^S0

#define N_CTX 2048
#define DH 64
#define KT 64
#define NKT (N_CTX / KT)
#define ROWS 128          // 8 waves x 16 q-rows
#define QS 72             // Qs/Ps row stride (f16)
#define HEAD_ELEMS (N_CTX * DH)   // 131072 f16 per head

#define C2 2.885390081777927f     // 2*log2(e), folded into staged Q

__device__ inline unsigned pk(float a, float b) {
    typedef __fp16 fp16x2_t __attribute__((ext_vector_type(2)));
    union { fp16x2_t v; unsigned u; } x;
    x.v = __builtin_amdgcn_cvt_pkrtz(a, b);
    return x.u;
}

__device__ inline void load16_lds(const f16* g, f16* l) {
    __builtin_amdgcn_global_load_lds(
        (const __attribute__((address_space(1))) void*)g,
        (__attribute__((address_space(3))) void*)l, 16, 0, 0);
}

// ---- pass0a: K f32 -> f16, same layout ----
__global__ __launch_bounds__(256)
void cvt_k(const float* __restrict__ k, f16* __restrict__ out) {
    int i = (blockIdx.x * 256 + threadIdx.x) * 8;
    float4 a = *(const float4*)&k[i];
    float4 b = *(const float4*)&k[i + 4];
    uint4 r = make_uint4(pk(a.x, a.y), pk(a.z, a.w), pk(b.x, b.y), pk(b.z, b.w));
    *(uint4*)&out[i] = r;
}

// ---- pass0b: V f32 [h][key][d] -> f16 [h][d][key] ----
__global__ __launch_bounds__(256)
void cvt_vt(const float* __restrict__ v, f16* __restrict__ out) {
    __shared__ float Vs[64][65];
    const int bh = blockIdx.x >> 5;          // head
    const int kt = blockIdx.x & 31;          // key tile
    const int t  = threadIdx.x;
    const float* vb = v + (size_t)bh * HEAD_ELEMS + (size_t)kt * KT * DH;
    // load 64x64 f32 coalesced
    #pragma unroll
    for (int it = 0; it < 4; ++it) {
        int idx = it * 256 + t;
        int row = idx >> 4, c4 = idx & 15;
        float4 x = *(const float4*)&vb[row * DH + c4 * 4];
        *(float4*)&Vs[row][c4 * 4] = x;
    }
    __syncthreads();
    // write transposed: thread t -> d = t>>2, keys kq*16..+15
    int d = t >> 2, kq = t & 3;
    unsigned w[8];
    #pragma unroll
    for (int j = 0; j < 8; ++j)
        w[j] = pk(Vs[kq * 16 + 2 * j][d], Vs[kq * 16 + 2 * j + 1][d]);
    f16* ob = out + (size_t)bh * HEAD_ELEMS + (size_t)d * N_CTX + kt * KT + kq * 16;
    *(uint4*)(ob)     = make_uint4(w[0], w[1], w[2], w[3]);
    *(uint4*)(ob + 8) = make_uint4(w[4], w[5], w[6], w[7]);
}

// ---- main ----
__global__ __launch_bounds__(512, 4)
void stk_attn_mfma(const float* __restrict__ qg, const f16* __restrict__ kh,
                   const f16* __restrict__ vth, const float* __restrict__ sg,
                   float* __restrict__ og) {
    __shared__ f16 Qs[ROWS * QS];       // 18432 B
    __shared__ f16 Ks[2][KT * DH];      // 16384 B swizzled chunks: p = key*8 + (dc^(key&7))
    __shared__ f16 Vt[2][DH * KT];      // 16384 B swizzled chunks: p = d*8 + (kc^(d&7))
    __shared__ f16 Ps[8][16 * QS];      // 18432 B wave-private [lrow][key], stride 72
                                        // total 69632 B

    const int tid  = threadIdx.x;
    const int wv   = tid >> 6;        // 0..7
    const int lane = tid & 63;
    const int l15  = lane & 15;
    const int q4   = lane >> 4;
    const int bh   = blockIdx.x & 31; // XCD swizzle
    const int q0   = (blockIdx.x >> 5) * ROWS;
    const float scale2 = sg[0] * C2;  // acc = 2L*log2e

    const float* qb = qg + (size_t)bh * HEAD_ELEMS;
    const f16*   kb = kh + (size_t)bh * HEAD_ELEMS;
    const f16*   vtb = vth + (size_t)bh * HEAD_ELEMS;
    float*       ob = og + (size_t)bh * HEAD_ELEMS;

    // ---- stage Q (scale2 folded) ----
    #pragma unroll
    for (int it = 0; it < 4; ++it) {
        int idx = it * 512 + tid;
        int row = idx >> 4, c4 = idx & 15;
        float4 v = *(const float4*)&qb[((size_t)(q0 + row)) * DH + c4 * 4];
        *(uint2*)&Qs[row * QS + c4 * 4] =
            make_uint2(pk(v.x * scale2, v.y * scale2), pk(v.z * scale2, v.w * scale2));
    }
    __syncthreads();

    // ---- Q A-fragments (loop-invariant) ----
    f16x8 aq[2];
    #pragma unroll
    for (int kc = 0; kc < 2; ++kc)
        aq[kc] = *(const f16x8*)&Qs[(wv * 16 + l15) * QS + kc * 32 + q4 * 8];

    // ---- loop-invariant staging source offsets & LDS read bases ----
    // K staging: chunk c = wv*64+lane; key = c>>3; logical dchunk = (c&7)^(key&7)
    const int kc_   = wv * 64 + lane;
    const int kkey  = kc_ >> 3;
    const int kdl   = (kc_ & 7) ^ (kkey & 7);
    const int ks_src = kkey * DH + kdl * 8;        // f16 elems within tile
    // V staging: d = c>>3 (= kkey); logical kchunk = (c&7)^(d&7) (= kdl)
    const long vt_src = (long)kkey * N_CTX + kdl * 8;  // + kt*KT per tile
    f16* const ks_dst0 = &Ks[0][wv * 512];
    f16* const vt_dst0 = &Vt[0][wv * 512];
    // K fragment reads: logical (key=kgi*16+l15, dchunk q4 / q4+4)
    const int ko0 = l15 * 64 + ((q4 ^ (l15 & 7)) * 8);
    const int ko1 = l15 * 64 + (((q4 + 4) ^ (l15 & 7)) * 8);
    // V fragment reads: d = dt*16+l15, kchunk = 4*kc+q4
    const int vo0 = l15 * 64 + ((q4 ^ (l15 & 7)) * 8);        // kc=0
    const int vo1 = l15 * 64 + (((4 + q4) ^ (l15 & 7)) * 8);  // kc=1
    // Ps
    f16* const ps_w = &Ps[wv][(q4 * 4) * QS + l15];
    const f16* const ps_r = &Ps[wv][l15 * QS + q4 * 8];

    // =============== PASS 1: s1 = sum exp(2L) ===============
    float s1[4] = {0, 0, 0, 0};
    load16_lds(kb + ks_src, ks_dst0);          // K(0) -> Ks[0]
    __syncthreads();
    for (int kt = 0; kt < NKT; ++kt) {
        const int cur = kt & 1;
        if (kt + 1 < NKT)
            load16_lds(kb + (kt + 1) * (KT * DH) + ks_src, ks_dst0 + (cur ^ 1) * (KT * DH));
        #pragma unroll
        for (int kgi = 0; kgi < 4; ++kgi) {
            f16x8 b0 = *(const f16x8*)&Ks[cur][kgi * 1024 + ko0];
            f16x8 b1 = *(const f16x8*)&Ks[cur][kgi * 1024 + ko1];
            f32x4 acc = {0.f, 0.f, 0.f, 0.f};
            acc = MFMA(aq[0], b0, acc);
            acc = MFMA(aq[1], b1, acc);
            #pragma unroll
            for (int r = 0; r < 4; ++r)
                s1[r] += EXP2(acc[r]);
        }
        __syncthreads();   // also drains the global_load_lds for Ks[nxt]
    }
    float inv1[4];
    #pragma unroll
    for (int s = 0; s < 4; ++s) {
        float v = s1[s];
        v += __shfl_xor(v, 1, 64);
        v += __shfl_xor(v, 2, 64);
        v += __shfl_xor(v, 4, 64);
        v += __shfl_xor(v, 8, 64);
        inv1[s] = 0.5f / v;      // e2 = exp2((acc*e1) * 0.5/s1)  [acc = 2L*log2e]
    }

    // =============== PASS 2: e2, O += e2*V ===============
    float l2[4] = {0, 0, 0, 0};
    f32x4 O[4];
    #pragma unroll
    for (int dt = 0; dt < 4; ++dt) O[dt] = (f32x4){0.f, 0.f, 0.f, 0.f};

    load16_lds(kb + ks_src, ks_dst0);          // K(0) -> Ks[0]
    load16_lds(vtb + vt_src, vt_dst0);         // V(0) -> Vt[0]
    __syncthreads();
    for (int kt = 0; kt < NKT; ++kt) {
        const int cur = kt & 1;
        if (kt + 1 < NKT) {
            load16_lds(kb + (kt + 1) * (KT * DH) + ks_src, ks_dst0 + (cur ^ 1) * (KT * DH));
            load16_lds(vtb + vt_src + (kt + 1) * KT, vt_dst0 + (cur ^ 1) * (DH * KT));
        }
        // QK^T + softmax chain + Ps write (wave-private, lgkmcnt-ordered)
        #pragma unroll
        for (int kgi = 0; kgi < 4; ++kgi) {
            f16x8 b0 = *(const f16x8*)&Ks[cur][kgi * 1024 + ko0];
            f16x8 b1 = *(const f16x8*)&Ks[cur][kgi * 1024 + ko1];
            f32x4 acc = {0.f, 0.f, 0.f, 0.f};
            acc = MFMA(aq[0], b0, acc);
            acc = MFMA(aq[1], b1, acc);
            #pragma unroll
            for (int r = 0; r < 4; ++r) {
                float a  = acc[r];
                float e1 = EXP2(a);
                float e2 = EXP2((a * e1) * inv1[r]);
                l2[r] += e2;
                ps_w[r * QS + kgi * 16] = (f16)e2;
            }
        }
        // PV from wave-private Ps + Vt[cur]
        #pragma unroll
        for (int kc = 0; kc < 2; ++kc) {
            f16x8 ap = *(const f16x8*)&ps_r[kc * 32];
            const int vo = (kc == 0) ? vo0 : vo1;
            #pragma unroll
            for (int dt = 0; dt < 4; ++dt) {
                f16x8 bv = *(const f16x8*)&Vt[cur][dt * 1024 + vo];
                O[dt] = MFMA(ap, bv, O[dt]);
            }
        }
        __syncthreads();   // protects Ks/Vt swap; drains async loads
    }

    // ---- finalize ----
    float invl2[4];
    #pragma unroll
    for (int s = 0; s < 4; ++s) {
        float v = l2[s];
        v += __shfl_xor(v, 1, 64);
        v += __shfl_xor(v, 2, 64);
        v += __shfl_xor(v, 4, 64);
        v += __shfl_xor(v, 8, 64);
        invl2[s] = 1.0f / v;
    }
    #pragma unroll
    for (int dt = 0; dt < 4; ++dt)
        #pragma unroll
        for (int r = 0; r < 4; ++r) {
            int row = q0 + wv * 16 + q4 * 4 + r;
            ob[(size_t)row * DH + dt * 16 + l15] = O[dt][r] * invl2[r];
        }
}

extern "C" void kernel_launch(void* const* d_in, const int* in_sizes, int n_in,
                              void* d_out, int out_size, void* d_ws, size_t ws_size,
                              hipStream_t stream) {
    const float* q = (const float*)d_in[0];
    const float* k = (const float*)d_in[1];
    const float* v = (const float*)d_in[2];
    const float* s = (const float*)d_in[3];
    float* out = (float*)d_out;
    f16* kf = (f16*)d_ws;                              // 8,388,608 B
    f16* vtf = (f16*)((char*)d_ws + 8388608);          // 8,388,608 B
    cvt_k<<<2048, 256, 0, stream>>>(k, kf);            // 32*2048*64 f32 -> f16
    cvt_vt<<<1024, 256, 0, stream>>>(v, vtf);          // transpose to [h][d][key]
    dim3 grid(32 * 16);   // bh = blockIdx&31 (XCD swizzle), q-tile = blockIdx>>5
    stk_attn_mfma<<<grid, 512, 0, stream>>>(q, kf, vtf, s, out);
}